// Round 1
// baseline (88.382 us; speedup 1.0000x reference)
//
#include <hip/hip_runtime.h>

#define N_POINTS 663552   // 6*2*192*288
#define M 16

__global__ __launch_bounds__(256) void crps_kernel(
    const float* __restrict__ target,
    const float* __restrict__ pred,
    float* __restrict__ out)
{
    const int quad = blockIdx.x * blockDim.x + threadIdx.x;  // one float4 (4 points) per thread
    const int p = quad * 4;

    float acc = 0.0f;
    if (p < N_POINTS) {
        const float4 t4 = *reinterpret_cast<const float4*>(target + p);
        float xv[4][M];  // [component][ensemble] — all indices compile-time after unroll
        #pragma unroll
        for (int i = 0; i < M; ++i) {
            const float4 v = *reinterpret_cast<const float4*>(pred + i * N_POINTS + p);
            xv[0][i] = v.x; xv[1][i] = v.y; xv[2][i] = v.z; xv[3][i] = v.w;
        }
        const float tv[4] = {t4.x, t4.y, t4.z, t4.w};

        #pragma unroll
        for (int k = 0; k < 4; ++k) {
            float skill = 0.0f;
            #pragma unroll
            for (int i = 0; i < M; ++i)
                skill += fabsf(xv[k][i] - tv[k]);

            float spread = 0.0f;
            #pragma unroll
            for (int i = 0; i < M; ++i)
                #pragma unroll
                for (int j = i + 1; j < M; ++j)
                    spread += fabsf(xv[k][i] - xv[k][j]);

            // skill/16 - spread/240  (ALPHA=1 -> epsilon=0)
            acc += skill * (1.0f / 16.0f) - spread * (1.0f / 240.0f);
        }
    }

    acc *= (1.0f / (float)N_POINTS);  // global mean contribution

    // wave(64) shuffle reduction
    #pragma unroll
    for (int off = 32; off > 0; off >>= 1)
        acc += __shfl_down(acc, off);

    __shared__ float wpart[4];
    const int lane = threadIdx.x & 63;
    const int wid  = threadIdx.x >> 6;
    if (lane == 0) wpart[wid] = acc;
    __syncthreads();
    if (threadIdx.x == 0) {
        float s = wpart[0] + wpart[1] + wpart[2] + wpart[3];
        atomicAdd(out, s);
    }
}

extern "C" void kernel_launch(void* const* d_in, const int* in_sizes, int n_in,
                              void* d_out, int out_size, void* d_ws, size_t ws_size,
                              hipStream_t stream) {
    const float* target = (const float*)d_in[0];  // (1,6,2,192,288)
    const float* pred   = (const float*)d_in[1];  // (16,6,2,192,288)
    float* out = (float*)d_out;                   // scalar

    // d_out is poisoned 0xAA before every call — zero it (stream-ordered, capture-safe)
    hipMemsetAsync(out, 0, sizeof(float), stream);

    const int threads = 256;
    const int quads = N_POINTS / 4;               // 165888, divisible by 256
    const int blocks = quads / threads;           // 648
    crps_kernel<<<blocks, threads, 0, stream>>>(target, pred, out);
}

// Round 4
// 83.408 us; speedup vs baseline: 1.0596x; 1.0596x over previous
//
#include <hip/hip_runtime.h>

#define N_POINTS 663552   // 6*2*192*288
#define M 16
#define NBLOCKS 648       // (N_POINTS/4) / 256

__global__ __launch_bounds__(256) void crps_main(
    const float* __restrict__ target,
    const float* __restrict__ pred,
    float* __restrict__ partials)   // d_ws: one float per block (pure overwrite, no init)
{
    const int quad = blockIdx.x * blockDim.x + threadIdx.x;  // one float4 (4 points) per thread
    const int p = quad * 4;

    float acc = 0.0f;
    {
        const float4 t4 = *reinterpret_cast<const float4*>(target + p);
        float xv[4][M];  // [component][ensemble] — compile-time indices after unroll
        #pragma unroll
        for (int i = 0; i < M; ++i) {
            const float4 v = *reinterpret_cast<const float4*>(pred + i * N_POINTS + p);
            xv[0][i] = v.x; xv[1][i] = v.y; xv[2][i] = v.z; xv[3][i] = v.w;
        }
        const float tv[4] = {t4.x, t4.y, t4.z, t4.w};

        #pragma unroll
        for (int k = 0; k < 4; ++k) {
            float skill = 0.0f;
            #pragma unroll
            for (int i = 0; i < M; ++i)
                skill += fabsf(xv[k][i] - tv[k]);

            float spread = 0.0f;
            #pragma unroll
            for (int i = 0; i < M; ++i)
                #pragma unroll
                for (int j = i + 1; j < M; ++j)
                    spread += fabsf(xv[k][i] - xv[k][j]);

            // skill/16 - spread/240  (ALPHA=1 -> epsilon=0)
            acc += skill * (1.0f / 16.0f) - spread * (1.0f / 240.0f);
        }
    }

    acc *= (1.0f / (float)N_POINTS);  // global-mean contribution

    // wave(64) shuffle reduction
    #pragma unroll
    for (int off = 32; off > 0; off >>= 1)
        acc += __shfl_down(acc, off);

    __shared__ float wpart[4];
    const int lane = threadIdx.x & 63;
    const int wid  = threadIdx.x >> 6;
    if (lane == 0) wpart[wid] = acc;
    __syncthreads();
    if (threadIdx.x == 0)
        partials[blockIdx.x] = wpart[0] + wpart[1] + wpart[2] + wpart[3];
}

__global__ __launch_bounds__(256) void crps_reduce(
    const float* __restrict__ partials,
    float* __restrict__ out)
{
    float s = 0.0f;
    for (int i = threadIdx.x; i < NBLOCKS; i += 256)
        s += partials[i];

    #pragma unroll
    for (int off = 32; off > 0; off >>= 1)
        s += __shfl_down(s, off);

    __shared__ float wpart[4];
    const int lane = threadIdx.x & 63;
    const int wid  = threadIdx.x >> 6;
    if (lane == 0) wpart[wid] = s;
    __syncthreads();
    if (threadIdx.x == 0)
        out[0] = wpart[0] + wpart[1] + wpart[2] + wpart[3];
}

extern "C" void kernel_launch(void* const* d_in, const int* in_sizes, int n_in,
                              void* d_out, int out_size, void* d_ws, size_t ws_size,
                              hipStream_t stream) {
    const float* target = (const float*)d_in[0];  // (1,6,2,192,288)
    const float* pred   = (const float*)d_in[1];  // (16,6,2,192,288)
    float* out      = (float*)d_out;              // scalar
    float* partials = (float*)d_ws;               // NBLOCKS floats of scratch

    crps_main<<<NBLOCKS, 256, 0, stream>>>(target, pred, partials);
    crps_reduce<<<1, 256, 0, stream>>>(partials, out);
}